// Round 6
// baseline (814.008 us; speedup 1.0000x reference)
//
#include <hip/hip_runtime.h>
#include <hip/hip_fp16.h>
#include <stdint.h>

#define N_NODES 50000
#define CAP 64          // max in-degree kept (deg ~ Poisson(16); P(>64) ~ 1e-10)
#define NBLK 1024
#define NTHR 256
#define TOTAL (NBLK * NTHR)

// ---------------------------------------------------------------------------
// Manual grid barrier (device/agent scope). Requires all NBLK blocks
// co-resident: __launch_bounds__(256,8) => VGPR<=64 => 8 blocks/CU capacity
// (2048 blocks) on 256 CUs; we launch 1024 (2x margin, zero LDS).
// bar[0]=arrival counter, bar[1]=release phase; memset to 0 before launch.
// ---------------------------------------------------------------------------
__device__ __forceinline__ void gsync(int* bar, int phase) {
    __syncthreads();
    if (threadIdx.x == 0) {
        __threadfence();  // agent-scope release (L2 writeback on gfx950)
        int old = __hip_atomic_fetch_add(&bar[0], 1, __ATOMIC_ACQ_REL,
                                         __HIP_MEMORY_SCOPE_AGENT);
        if (old == NBLK - 1) {
            __hip_atomic_store(&bar[0], 0, __ATOMIC_RELAXED,
                               __HIP_MEMORY_SCOPE_AGENT);
            __hip_atomic_store(&bar[1], phase, __ATOMIC_RELEASE,
                               __HIP_MEMORY_SCOPE_AGENT);
        } else {
            while (__hip_atomic_load(&bar[1], __ATOMIC_ACQUIRE,
                                     __HIP_MEMORY_SCOPE_AGENT) < phase)
                __builtin_amdgcn_s_sleep(2);
        }
    }
    __syncthreads();
}

// ---------------------------------------------------------------------------
// One persistent kernel, 5 phases:
//  A: zero cursor; fold weight constants into pc
//  B: bucket build (atomic per-dst slots, ushort src ids)
//  C: dis = rsqrt(deg+1); xd[n] = x[b,n]*dis[n] (float4 over batches)
//  D: layer-1 (rank-1 agg, 8 lanes/node) + folded GRU gates -> hs fp16 [n][f][b]
//  E: layer-2 agg (fp16 pk_add gather, readlane indices) + folded gates + Wout
// pc layout: [0..1023] M0, [1024..2047] M2, [2048..2111] w0|w2,
//            [2112..2239] uz|vz|uh|vh  (H=0 kills reset gate; Wl rows 32..63)
// ---------------------------------------------------------------------------
__global__ __launch_bounds__(NTHR, 8) void mega_kernel(
    const float* __restrict__ x, const int* __restrict__ src,
    const int* __restrict__ dst, const float* __restrict__ Wc1,
    const float* __restrict__ bc1, const float* __restrict__ Wl1,
    const float* __restrict__ bl1, const float* __restrict__ Wc2,
    const float* __restrict__ bc2, const float* __restrict__ Wl2,
    const float* __restrict__ bl2, const float* __restrict__ Wout,
    const float* __restrict__ bout, float* __restrict__ out,
    int* __restrict__ cursor, unsigned short* __restrict__ bucket,
    float* __restrict__ dis, float4* __restrict__ xd, char* __restrict__ hs,
    float* __restrict__ pc, int* bar, int E, int N) {
    const int tid = blockIdx.x * NTHR + threadIdx.x;

    // ---- Phase A: zero cursor + precompute folded constants ----
    if (tid < N) cursor[tid] = 0;
    if (tid < 2240) {
        int i = tid;
        if (i < 2048) {
            int g = i >> 10;
            int kf = i & 1023;
            int k = kf >> 5, f = kf & 31;
            int gate = g ? 2 : 0;
            float s = 0.0f;
            for (int j = 0; j < 32; ++j)
                s += Wc2[gate * 1024 + k * 32 + j] *
                     Wl2[gate * 2048 + j * 32 + f];
            pc[i] = s;
        } else if (i < 2112) {
            int g = (i - 2048) >> 5;
            int f = i & 31;
            int gate = g ? 2 : 0;
            float s = bl2[gate * 32 + f];
            for (int j = 0; j < 32; ++j)
                s += bc2[gate * 32 + j] * Wl2[gate * 2048 + j * 32 + f];
            pc[i] = s;
        } else {
            int t = i - 2112;
            int which = t >> 5;
            int f = t & 31;
            int gate = (which >= 2) ? 2 : 0;
            if ((which & 1) == 0) {
                float s = 0.0f;
                for (int j = 0; j < 32; ++j)
                    s += Wc1[gate * 32 + j] * Wl1[gate * 2048 + j * 32 + f];
                pc[i] = s;
            } else {
                float s = bl1[gate * 32 + f];
                for (int j = 0; j < 32; ++j)
                    s += bc1[gate * 32 + j] * Wl1[gate * 2048 + j * 32 + f];
                pc[i] = s;
            }
        }
    }
    gsync(bar, 1);

    // ---- Phase B: bucket build ----
    for (int e = tid; e < E; e += TOTAL) {
        int d = dst[e];
        int pos = atomicAdd(&cursor[d], 1);
        if (pos < CAP) bucket[d * CAP + pos] = (unsigned short)src[e];
    }
    gsync(bar, 2);

    // ---- Phase C: dis + xd ----
    if (tid < N) {
        float d = rsqrtf((float)(cursor[tid] + 1));
        dis[tid] = d;
        xd[tid] = make_float4(x[tid] * d, x[N + tid] * d, x[2 * N + tid] * d,
                              x[3 * N + tid] * d);
    }
    gsync(bar, 3);

    // ---- Phase D: layer-1 agg + gates -> hs (fp16 [n][f][b]) ----
    for (int idx = tid; idx < N * 8; idx += TOTAL) {
        int node = idx >> 3;
        int j = idx & 7;
        int cnt = cursor[node];
        if (cnt > CAP) cnt = CAP;
        float ax, ay, az, aw;
        if (j == 0) {
            float4 v = xd[node];  // self loop
            ax = v.x; ay = v.y; az = v.z; aw = v.w;
        } else {
            ax = ay = az = aw = 0.f;
        }
        for (int i = j; i < cnt; i += 8) {
            int s = bucket[node * CAP + i];
            float4 v = xd[s];
            ax += v.x; ay += v.y; az += v.z; aw += v.w;
        }
#pragma unroll
        for (int m = 4; m; m >>= 1) {
            ax += __shfl_xor(ax, m, 64);
            ay += __shfl_xor(ay, m, 64);
            az += __shfl_xor(az, m, 64);
            aw += __shfl_xor(aw, m, 64);
        }
        float d = dis[node];
        float t0 = ax * d, t1 = ay * d, t2 = az * d, t3 = aw * d;
#pragma unroll
        for (int m = 0; m < 4; ++m) {
            int f = j + 8 * m;
            float uz = pc[2112 + f], vz = pc[2144 + f];
            float uh = pc[2176 + f], vh = pc[2208 + f];
            float h0 = fmaxf((1.0f - 1.0f / (1.0f + expf(-(t0 * uz + vz)))) *
                             tanhf(t0 * uh + vh), 0.0f) * d;
            float h1 = fmaxf((1.0f - 1.0f / (1.0f + expf(-(t1 * uz + vz)))) *
                             tanhf(t1 * uh + vh), 0.0f) * d;
            float h2 = fmaxf((1.0f - 1.0f / (1.0f + expf(-(t2 * uz + vz)))) *
                             tanhf(t2 * uh + vh), 0.0f) * d;
            float h3 = fmaxf((1.0f - 1.0f / (1.0f + expf(-(t3 * uz + vz)))) *
                             tanhf(t3 * uh + vh), 0.0f) * d;
            __half2 lo = __floats2half2_rn(h0, h1);
            __half2 hi = __floats2half2_rn(h2, h3);
            uint2 u;
            u.x = *reinterpret_cast<unsigned int*>(&lo);
            u.y = *reinterpret_cast<unsigned int*>(&hi);
            *reinterpret_cast<uint2*>(hs + (size_t)node * 256 + f * 8) = u;
        }
    }
    gsync(bar, 4);

    // ---- Phase E: layer-2 agg + gates + output projection ----
    {
        int lane = threadIdx.x & 63;
        int f = lane & 31;
        int h = lane >> 5;
        float mcol[32];
#pragma unroll
        for (int k = 0; k < 32; ++k) mcol[k] = pc[h * 1024 + k * 32 + f];
        float wv = pc[2048 + h * 32 + f];
        float wf = Wout[f];
        float bo = bout[0];
        const char* hp = hs + f * 8 + h * 4;

        int wid = tid >> 6;
        int nw = TOTAL >> 6;  // 4096 waves

        for (int node = wid; node < N; node += nw) {
            int cnt = cursor[node];
            if (cnt > CAP) cnt = CAP;
            unsigned int bidx = bucket[node * CAP + lane];
            __half2 acc = *(const __half2*)(hp + (size_t)node * 256);  // self
            int i = 0;
            for (; i + 8 <= cnt; i += 8) {
                unsigned int o0 = __builtin_amdgcn_readlane(bidx, i) * 256u;
                unsigned int o1 = __builtin_amdgcn_readlane(bidx, i + 1) * 256u;
                unsigned int o2 = __builtin_amdgcn_readlane(bidx, i + 2) * 256u;
                unsigned int o3 = __builtin_amdgcn_readlane(bidx, i + 3) * 256u;
                unsigned int o4 = __builtin_amdgcn_readlane(bidx, i + 4) * 256u;
                unsigned int o5 = __builtin_amdgcn_readlane(bidx, i + 5) * 256u;
                unsigned int o6 = __builtin_amdgcn_readlane(bidx, i + 6) * 256u;
                unsigned int o7 = __builtin_amdgcn_readlane(bidx, i + 7) * 256u;
                __half2 v0 = *(const __half2*)(hp + o0);
                __half2 v1 = *(const __half2*)(hp + o1);
                __half2 v2 = *(const __half2*)(hp + o2);
                __half2 v3 = *(const __half2*)(hp + o3);
                __half2 v4 = *(const __half2*)(hp + o4);
                __half2 v5 = *(const __half2*)(hp + o5);
                __half2 v6 = *(const __half2*)(hp + o6);
                __half2 v7 = *(const __half2*)(hp + o7);
                __half2 s01 = __hadd2(v0, v1);
                __half2 s23 = __hadd2(v2, v3);
                __half2 s45 = __hadd2(v4, v5);
                __half2 s67 = __hadd2(v6, v7);
                __half2 s03 = __hadd2(s01, s23);
                __half2 s47 = __hadd2(s45, s67);
                acc = __hadd2(acc, __hadd2(s03, s47));
            }
            for (; i < cnt; ++i) {
                unsigned int o = __builtin_amdgcn_readlane(bidx, i) * 256u;
                acc = __hadd2(acc, *(const __half2*)(hp + o));
            }
            float2 fa = __half22float2(acc);
            float accx = fa.x, accy = fa.y;

            float g0 = 0.f, g1 = 0.f, g2 = 0.f, g3 = 0.f;
#pragma unroll
            for (int k = 0; k < 32; ++k) {
                float tb0 = __int_as_float(
                    __builtin_amdgcn_readlane(__float_as_int(accx), k));
                float tb1 = __int_as_float(
                    __builtin_amdgcn_readlane(__float_as_int(accy), k));
                float tb2 = __int_as_float(
                    __builtin_amdgcn_readlane(__float_as_int(accx), 32 + k));
                float tb3 = __int_as_float(
                    __builtin_amdgcn_readlane(__float_as_int(accy), 32 + k));
                float m = mcol[k];
                g0 += tb0 * m; g1 += tb1 * m; g2 += tb2 * m; g3 += tb3 * m;
            }
            float dn = dis[node];
            float a0 = dn * g0 + wv, a1 = dn * g1 + wv;
            float a2 = dn * g2 + wv, a3 = dn * g3 + wv;
            // one tanh per value: sigmoid(a) = 0.5 + 0.5*tanh(a/2)
            float sc = h ? 1.0f : 0.5f;
            float q0 = tanhf(a0 * sc), q1 = tanhf(a1 * sc);
            float q2 = tanhf(a2 * sc), q3 = tanhf(a3 * sc);
            float v0 = h ? q0 : fmaf(0.5f, q0, 0.5f);
            float v1 = h ? q1 : fmaf(0.5f, q1, 0.5f);
            float v2 = h ? q2 : fmaf(0.5f, q2, 0.5f);
            float v3 = h ? q3 : fmaf(0.5f, q3, 0.5f);
            float p0 = __shfl_xor(v0, 32, 64);
            float p1 = __shfl_xor(v1, 32, 64);
            float p2 = __shfl_xor(v2, 32, 64);
            float p3 = __shfl_xor(v3, 32, 64);
            if (h == 0) {
                float o0 = fmaxf((1.0f - v0) * p0, 0.0f) * wf;
                float o1 = fmaxf((1.0f - v1) * p1, 0.0f) * wf;
                float o2 = fmaxf((1.0f - v2) * p2, 0.0f) * wf;
                float o3 = fmaxf((1.0f - v3) * p3, 0.0f) * wf;
#pragma unroll
                for (int d = 16; d; d >>= 1) {
                    o0 += __shfl_xor(o0, d, 64);
                    o1 += __shfl_xor(o1, d, 64);
                    o2 += __shfl_xor(o2, d, 64);
                    o3 += __shfl_xor(o3, d, 64);
                }
                if (f == 0) {
                    out[node] = o0 + bo;
                    out[(size_t)N + node] = o1 + bo;
                    out[(size_t)2 * N + node] = o2 + bo;
                    out[(size_t)3 * N + node] = o3 + bo;
                }
            }
        }
    }
}

// ---------------------------------------------------------------------------

extern "C" void kernel_launch(void* const* d_in, const int* in_sizes, int n_in,
                              void* d_out, int out_size, void* d_ws,
                              size_t ws_size, hipStream_t stream) {
    const float* x    = (const float*)d_in[0];
    const int*   ei   = (const int*)d_in[1];
    const float* Wc1  = (const float*)d_in[2];
    const float* bc1  = (const float*)d_in[3];
    const float* Wl1  = (const float*)d_in[4];
    const float* bl1  = (const float*)d_in[5];
    // d_in[6] att1: softmax over 1 element == 1.0
    const float* Wc2  = (const float*)d_in[7];
    const float* bc2  = (const float*)d_in[8];
    const float* Wl2  = (const float*)d_in[9];
    const float* bl2  = (const float*)d_in[10];
    // d_in[11] att2 unused
    const float* Wout = (const float*)d_in[12];
    const float* bout = (const float*)d_in[13];

    const int E = in_sizes[1] / 2;
    const int N = N_NODES;
    const int* src = ei;
    const int* dst = ei + E;

    char* p = (char*)d_ws;
    auto alloc = [&](size_t bytes) {
        char* r = p;
        p += (bytes + 15) & ~(size_t)15;
        return r;
    };
    int*            bar    = (int*)alloc(4 * sizeof(int));
    int*            cursor = (int*)alloc(N * sizeof(int));
    unsigned short* bucket = (unsigned short*)alloc((size_t)N * CAP * 2);
    float*          dis    = (float*)alloc(N * sizeof(float));
    float*          xd     = (float*)alloc((size_t)N * 4 * sizeof(float));
    char*           hs     = (char*)alloc((size_t)N * 256);  // fp16 [n][f][b]
    float*          pc     = (float*)alloc(2240 * sizeof(float));

    hipMemsetAsync(bar, 0, 4 * sizeof(int), stream);  // barrier state only

    mega_kernel<<<NBLK, NTHR, 0, stream>>>(
        x, src, dst, Wc1, bc1, Wl1, bl1, Wc2, bc2, Wl2, bl2, Wout, bout,
        (float*)d_out, cursor, bucket, dis, (float4*)xd, hs, pc, bar, E, N);
}

// Round 7
// 219.134 us; speedup vs baseline: 3.7147x; 3.7147x over previous
//
#include <hip/hip_runtime.h>
#include <hip/hip_fp16.h>
#include <stdint.h>

#define N_NODES 50000
#define BATCH 4
#define CAP 64  // max in-degree (deg ~ Poisson(16); P(>64) ~ 1e-10)

// ---------------------------------------------------------------------------
// Merged: zero cursor + fold weight constants into pc (independent work).
//  pc[0..1023]    M0 = Wc2[0]@Wl2[0][:32]      pc[1024..2047]  M2 (gate 2)
//  pc[2048..2079] w0 = bc2[0]@Wl2[0]+bl2[0]    pc[2080..2111]  w2
//  pc[2112..2143] uz = Wc1[0]@Wl1[0]           pc[2144..2175]  vz
//  pc[2176..2207] uh (gate 2)                  pc[2208..2239]  vh
// (H=0 => reset gate dead; concat uses only rows 0..31 of each Wl)
// ---------------------------------------------------------------------------
__global__ void zero_precomp_kernel(int* __restrict__ cursor,
                                    const float* __restrict__ Wc1,
                                    const float* __restrict__ bc1,
                                    const float* __restrict__ Wl1,
                                    const float* __restrict__ bl1,
                                    const float* __restrict__ Wc2,
                                    const float* __restrict__ bc2,
                                    const float* __restrict__ Wl2,
                                    const float* __restrict__ bl2,
                                    float* __restrict__ pc, int N) {
    int i = blockIdx.x * blockDim.x + threadIdx.x;
    if (i < N) cursor[i] = 0;
    if (i >= 2240) return;
    if (i < 2048) {
        int g = i >> 10;
        int kf = i & 1023;
        int k = kf >> 5, f = kf & 31;
        int gate = g ? 2 : 0;
        float s = 0.0f;
        for (int j = 0; j < 32; ++j)
            s += Wc2[gate * 1024 + k * 32 + j] * Wl2[gate * 2048 + j * 32 + f];
        pc[i] = s;
    } else if (i < 2112) {
        int g = (i - 2048) >> 5;
        int f = i & 31;
        int gate = g ? 2 : 0;
        float s = bl2[gate * 32 + f];
        for (int j = 0; j < 32; ++j)
            s += bc2[gate * 32 + j] * Wl2[gate * 2048 + j * 32 + f];
        pc[i] = s;
    } else {
        int t = i - 2112;
        int which = t >> 5;
        int f = t & 31;
        int gate = (which >= 2) ? 2 : 0;
        if ((which & 1) == 0) {
            float s = 0.0f;
            for (int j = 0; j < 32; ++j)
                s += Wc1[gate * 32 + j] * Wl1[gate * 2048 + j * 32 + f];
            pc[i] = s;
        } else {
            float s = bl1[gate * 32 + f];
            for (int j = 0; j < 32; ++j)
                s += bc1[gate * 32 + j] * Wl1[gate * 2048 + j * 32 + f];
            pc[i] = s;
        }
    }
}

// ---------------------------------------------------------------------------
// Bucket CSR build: bucket[d][pos] = src (ushort). After: cursor[d] = deg(d).
// ---------------------------------------------------------------------------
__global__ void fill_kernel(const int* __restrict__ src,
                            const int* __restrict__ dst,
                            int* __restrict__ cursor,
                            unsigned short* __restrict__ bucket, int E) {
    int e = blockIdx.x * blockDim.x + threadIdx.x;
    if (e < E) {
        int d = dst[e];
        int pos = atomicAdd(&cursor[d], 1);
        if (pos < CAP) bucket[d * CAP + pos] = (unsigned short)src[e];
    }
}

// dis[n] = rsqrt(deg+1);  xd[n] = float4{x[b,n]*dis[n]}
__global__ void dis_xd_kernel(const int* __restrict__ deg,
                              const float* __restrict__ x,
                              float* __restrict__ dis,
                              float4* __restrict__ xd, int N) {
    int n = blockIdx.x * blockDim.x + threadIdx.x;
    if (n >= N) return;
    float d = rsqrtf((float)(deg[n] + 1));
    dis[n] = d;
    xd[n] = make_float4(x[n] * d, x[N + n] * d, x[2 * N + n] * d,
                        x[3 * N + n] * d);
}

// ---------------------------------------------------------------------------
// Fused layer 1: scalar agg (8 lanes/node, xor-reduce) + folded gates,
// writing hs[n][f][b] as fp16 (values ~3e-3 scale).
// ---------------------------------------------------------------------------
__global__ void s1h1_kernel(const float4* __restrict__ xd,
                            const float* __restrict__ dis,
                            const int* __restrict__ deg,
                            const unsigned short* __restrict__ bucket,
                            const float* __restrict__ pc,
                            char* __restrict__ hs, int N) {
    int idx = blockIdx.x * blockDim.x + threadIdx.x;
    int node = idx >> 3;
    if (node >= N) return;
    int j = idx & 7;
    int cnt = deg[node];
    if (cnt > CAP) cnt = CAP;
    float ax, ay, az, aw;
    if (j == 0) {
        float4 v = xd[node];  // self loop
        ax = v.x; ay = v.y; az = v.z; aw = v.w;
    } else {
        ax = ay = az = aw = 0.f;
    }
    for (int i = j; i < cnt; i += 8) {
        int s = bucket[node * CAP + i];
        float4 v = xd[s];
        ax += v.x; ay += v.y; az += v.z; aw += v.w;
    }
#pragma unroll
    for (int m = 4; m; m >>= 1) {
        ax += __shfl_xor(ax, m, 64);
        ay += __shfl_xor(ay, m, 64);
        az += __shfl_xor(az, m, 64);
        aw += __shfl_xor(aw, m, 64);
    }
    float d = dis[node];
    float t0 = ax * d, t1 = ay * d, t2 = az * d, t3 = aw * d;
#pragma unroll
    for (int m = 0; m < 4; ++m) {
        int f = j + 8 * m;
        float uz = pc[2112 + f], vz = pc[2144 + f];
        float uh = pc[2176 + f], vh = pc[2208 + f];
        float h0 = fmaxf((1.0f - 1.0f / (1.0f + expf(-(t0 * uz + vz)))) *
                         tanhf(t0 * uh + vh), 0.0f) * d;
        float h1 = fmaxf((1.0f - 1.0f / (1.0f + expf(-(t1 * uz + vz)))) *
                         tanhf(t1 * uh + vh), 0.0f) * d;
        float h2 = fmaxf((1.0f - 1.0f / (1.0f + expf(-(t2 * uz + vz)))) *
                         tanhf(t2 * uh + vh), 0.0f) * d;
        float h3 = fmaxf((1.0f - 1.0f / (1.0f + expf(-(t3 * uz + vz)))) *
                         tanhf(t3 * uh + vh), 0.0f) * d;
        __half2 lo = __floats2half2_rn(h0, h1);
        __half2 hi = __floats2half2_rn(h2, h3);
        uint2 u;
        u.x = *reinterpret_cast<unsigned int*>(&lo);
        u.y = *reinterpret_cast<unsigned int*>(&hi);
        *reinterpret_cast<uint2*>(hs + (size_t)node * 256 + f * 8) = u;
    }
}

// ---------------------------------------------------------------------------
// Layer-2 fused agg + gates + output projection. Grid-stride waves.
// Wave = node. Lane l: f=l&31, h=l>>5 owns batches {2h,2h+1} (half2 4B/edge).
// Gather: fp16 packed adds; indices broadcast via readlane (SGPR addressing).
// Tail: lane holds BOTH gates' M-columns (64 VGPR); T transposed through
// wave-private LDS (1 ds_write_b64 + 16 broadcast ds_read_b128 per node) —
// DS-pipe work that overlaps VALU, replacing 128 readlane + half the fmas
// of the R5 readlane-matvec. No cross-half shuffle needed.
// ---------------------------------------------------------------------------
__global__ __launch_bounds__(256) void l2_agg_kernel(
    const char* __restrict__ hs, const float* __restrict__ dis,
    const int* __restrict__ deg, const unsigned short* __restrict__ bucket,
    const float* __restrict__ pc, const float* __restrict__ Wout,
    const float* __restrict__ bout, float* __restrict__ out, int N) {
    __shared__ float2 sT[4][64];  // wave-private transpose scratch
    int wv = threadIdx.x >> 6;
    int lane = threadIdx.x & 63;
    int f = lane & 31;
    int h = lane >> 5;

    float wl0[32], wl2[32];
#pragma unroll
    for (int k = 0; k < 32; ++k) {
        wl0[k] = pc[k * 32 + f];          // M0 column f
        wl2[k] = pc[1024 + k * 32 + f];   // M2 column f
    }
    float w0 = pc[2048 + f], w2 = pc[2080 + f];
    float wf = Wout[f];
    float bo = bout[0];
    const char* hp = hs + f * 8 + h * 4;  // lane's half2 within a 256B row

    int wid = (blockIdx.x * blockDim.x + threadIdx.x) >> 6;
    int nw = (gridDim.x * blockDim.x) >> 6;

    for (int node = wid; node < N; node += nw) {
        int cnt = deg[node];
        if (cnt > CAP) cnt = CAP;
        unsigned int bidx = bucket[node * CAP + lane];  // 128B/wave coalesced
        __half2 acc = *(const __half2*)(hp + (size_t)node * 256);  // self loop
        int i = 0;
        for (; i + 8 <= cnt; i += 8) {
            unsigned int o0 = __builtin_amdgcn_readlane(bidx, i) * 256u;
            unsigned int o1 = __builtin_amdgcn_readlane(bidx, i + 1) * 256u;
            unsigned int o2 = __builtin_amdgcn_readlane(bidx, i + 2) * 256u;
            unsigned int o3 = __builtin_amdgcn_readlane(bidx, i + 3) * 256u;
            unsigned int o4 = __builtin_amdgcn_readlane(bidx, i + 4) * 256u;
            unsigned int o5 = __builtin_amdgcn_readlane(bidx, i + 5) * 256u;
            unsigned int o6 = __builtin_amdgcn_readlane(bidx, i + 6) * 256u;
            unsigned int o7 = __builtin_amdgcn_readlane(bidx, i + 7) * 256u;
            __half2 v0 = *(const __half2*)(hp + o0);
            __half2 v1 = *(const __half2*)(hp + o1);
            __half2 v2 = *(const __half2*)(hp + o2);
            __half2 v3 = *(const __half2*)(hp + o3);
            __half2 v4 = *(const __half2*)(hp + o4);
            __half2 v5 = *(const __half2*)(hp + o5);
            __half2 v6 = *(const __half2*)(hp + o6);
            __half2 v7 = *(const __half2*)(hp + o7);
            __half2 s01 = __hadd2(v0, v1);
            __half2 s23 = __hadd2(v2, v3);
            __half2 s45 = __hadd2(v4, v5);
            __half2 s67 = __hadd2(v6, v7);
            acc = __hadd2(acc, __hadd2(__hadd2(s01, s23), __hadd2(s45, s67)));
        }
        for (; i < cnt; ++i) {
            unsigned int o = __builtin_amdgcn_readlane(bidx, i) * 256u;
            acc = __hadd2(acc, *(const __half2*)(hp + o));
        }
        float2 fa = __half22float2(acc);  // (T[2h][f], T[2h+1][f])

        // transpose via wave-private LDS (no barrier; in-wave DS ordering)
        sT[wv][lane] = fa;

        float sz0 = 0.f, sz1 = 0.f, sh0 = 0.f, sh1 = 0.f;
        const float2* tp = &sT[wv][h * 32];  // this half's 32 (T0,T1) pairs
#pragma unroll
        for (int k = 0; k < 32; k += 2) {
            float4 t2 = *(const float4*)&tp[k];  // broadcast read, 2 k's
            sz0 += t2.x * wl0[k];     sz1 += t2.y * wl0[k];
            sh0 += t2.x * wl2[k];     sh1 += t2.y * wl2[k];
            sz0 += t2.z * wl0[k + 1]; sz1 += t2.w * wl0[k + 1];
            sh0 += t2.z * wl2[k + 1]; sh1 += t2.w * wl2[k + 1];
        }
        float dn = dis[node];
        float z0 = 1.0f / (1.0f + expf(-(dn * sz0 + w0)));
        float z1 = 1.0f / (1.0f + expf(-(dn * sz1 + w0)));
        float t0 = tanhf(dn * sh0 + w2);
        float t1 = tanhf(dn * sh1 + w2);
        float h20 = fmaxf((1.0f - z0) * t0, 0.0f);
        float h21 = fmaxf((1.0f - z1) * t1, 0.0f);

        float o0 = h20 * wf;
        float o1 = h21 * wf;
#pragma unroll
        for (int d = 16; d; d >>= 1) {  // reduce over f within each half
            o0 += __shfl_xor(o0, d, 64);
            o1 += __shfl_xor(o1, d, 64);
        }
        if (f == 0) {
            out[(size_t)(2 * h) * N + node] = o0 + bo;
            out[(size_t)(2 * h + 1) * N + node] = o1 + bo;
        }
    }
}

// ---------------------------------------------------------------------------

extern "C" void kernel_launch(void* const* d_in, const int* in_sizes, int n_in,
                              void* d_out, int out_size, void* d_ws,
                              size_t ws_size, hipStream_t stream) {
    const float* x    = (const float*)d_in[0];
    const int*   ei   = (const int*)d_in[1];
    const float* Wc1  = (const float*)d_in[2];
    const float* bc1  = (const float*)d_in[3];
    const float* Wl1  = (const float*)d_in[4];
    const float* bl1  = (const float*)d_in[5];
    // d_in[6] att1: softmax over 1 element == 1.0
    const float* Wc2  = (const float*)d_in[7];
    const float* bc2  = (const float*)d_in[8];
    const float* Wl2  = (const float*)d_in[9];
    const float* bl2  = (const float*)d_in[10];
    // d_in[11] att2 unused
    const float* Wout = (const float*)d_in[12];
    const float* bout = (const float*)d_in[13];

    const int E = in_sizes[1] / 2;
    const int N = N_NODES;
    const int* src = ei;
    const int* dst = ei + E;

    char* p = (char*)d_ws;
    auto alloc = [&](size_t bytes) {
        char* r = p;
        p += (bytes + 15) & ~(size_t)15;
        return r;
    };
    int*            cursor = (int*)alloc(N * sizeof(int));
    unsigned short* bucket = (unsigned short*)alloc((size_t)N * CAP * 2);
    float*          dis    = (float*)alloc(N * sizeof(float));
    float*          xd     = (float*)alloc((size_t)N * 4 * sizeof(float));
    char*           hs     = (char*)alloc((size_t)N * 256);  // fp16 [n][f][b]
    float*          pc     = (float*)alloc(2240 * sizeof(float));

    // 1) zero cursor + fold constants (one dispatch, no memset needed)
    zero_precomp_kernel<<<(N + 255) / 256, 256, 0, stream>>>(
        cursor, Wc1, bc1, Wl1, bl1, Wc2, bc2, Wl2, bl2, pc, N);

    // 2) bucket build
    fill_kernel<<<(E + 255) / 256, 256, 0, stream>>>(src, dst, cursor, bucket,
                                                     E);
    // 3) dis + xd
    dis_xd_kernel<<<(N + 255) / 256, 256, 0, stream>>>(cursor, x, dis,
                                                       (float4*)xd, N);
    // 4) layer 1 fused (agg + gates -> fp16 hs)
    s1h1_kernel<<<(N * 8 + 255) / 256, 256, 0, stream>>>(
        (const float4*)xd, dis, cursor, bucket, pc, hs, N);

    // 5) layer 2 fused (agg + gates + output projection)
    l2_agg_kernel<<<2048, 256, 0, stream>>>(hs, dis, cursor, bucket, pc, Wout,
                                            bout, (float*)d_out, N);
}